// Round 5
// baseline (561.970 us; speedup 1.0000x reference)
//
#include <hip/hip_runtime.h>
#include <stdint.h>

// QuantizedLinear: x[8,512,4096] fp32, W[11008,4096] int8-in-int32, scale[11008] fp32
#define M_DIM 4096
#define N_DIM 11008
#define K_DIM 4096

typedef int i32x4  __attribute__((ext_vector_type(4)));
typedef int i32x16 __attribute__((ext_vector_type(16)));

// async global->LDS, 16 bytes/lane. LDS dest = wave-uniform base + lane*16.
static __device__ __forceinline__ void direct_load16(const void* gptr, void* ldsptr) {
    __builtin_amdgcn_global_load_lds(
        (const __attribute__((address_space(1))) void*)gptr,
        (__attribute__((address_space(3))) void*)ldsptr,
        16, 0, 0);
}

// ---- W: int32 in [-127,127] -> int8, 4 elems/thread, coalesced both sides
__global__ __launch_bounds__(256) void cvt_w_kernel(const int* __restrict__ w,
                                                    int8_t* __restrict__ o) {
    int t = blockIdx.x * 256 + threadIdx.x;
    const int4* w4 = (const int4*)w;
    int4 a = w4[t];
    ((unsigned*)o)[t] = (a.x & 255) | ((a.y & 255) << 8) | ((a.z & 255) << 16) | (a.w << 24);
}

// ---- x: fp32 -> int8 with per-row absmax scale --------------------------
__global__ __launch_bounds__(256) void quant_x_kernel(const float* __restrict__ x,
                                                      int8_t* __restrict__ xq,
                                                      float* __restrict__ xs) {
    __shared__ float wmax[4];
    const int row = blockIdx.x;
    const int t = threadIdx.x;
    const float4* xr = (const float4*)(x + (size_t)row * K_DIM);

    float4 v[4];
    float am = 0.0f;
#pragma unroll
    for (int p = 0; p < 4; p++) {
        v[p] = xr[p * 256 + t];
        am = fmaxf(am, fmaxf(fmaxf(fabsf(v[p].x), fabsf(v[p].y)),
                             fmaxf(fabsf(v[p].z), fabsf(v[p].w))));
    }
#pragma unroll
    for (int o = 32; o > 0; o >>= 1)
        am = fmaxf(am, __shfl_xor(am, o));
    if ((t & 63) == 0) wmax[t >> 6] = am;
    __syncthreads();
    am = fmaxf(fmaxf(wmax[0], wmax[1]), fmaxf(wmax[2], wmax[3]));

    const float inv = 127.0f / am;
    int* oq = (int*)(xq + (size_t)row * K_DIM);
#pragma unroll
    for (int p = 0; p < 4; p++) {
        int qa = (int)rintf(v[p].x * inv);
        int qb = (int)rintf(v[p].y * inv);
        int qc = (int)rintf(v[p].z * inv);
        int qd = (int)rintf(v[p].w * inv);
        oq[p * 256 + t] = (qa & 255) | ((qb & 255) << 8) | ((qc & 255) << 16) | (qd << 24);
    }
    if (t == 0) xs[row] = am * (1.0f / 127.0f);
}

// ---- GEMM: C = (Aq . Bq^T) * xs[m] * ws[n] ------------------------------
// 256x256 tile, 512 thr = 8 waves (2M x 4N). Same software-pipelined
// 2-phase/tile schedule as round 4 (register ping-pong, 1 barrier +
// vmcnt(4) per phase, depth-3 staging into 4 LDS buffers), but MFMA shape
// switched 16x16x64 -> 32x32x32 i8 (measured ceiling 3944 -> 4404 TOPS,
// half the MFMA instructions at identical fragment bytes).
//
// Per wave: out 128x64 = 4(ai) x 2(bj) tiles of 32x32, acc 128 regs.
// Per phase (k-step ks of K=64): 4 A frags + 2 B frags (6 ds_read_b128),
// 8 MFMA. A/B frag layout (32x32x32): row/col = lane&31, k = (lane>>5)*16.
// LDS chunk for k-step ks: phys = ((ks*2 + (lane>>5)) ^ fsw), fsw =
// ((lane&31)>>1)&3 (XOR swizzle, store side unchanged). C/D: col=lane&31,
// row = (reg&3) + 8*(reg>>2) + 4*(lane>>5)  [m74/m101-verified mapping].
//
// Staging/vmcnt race analysis identical to round 4: tile t's phases stage
// tile t+3 (A in h0, B in h1); vmcnt(4) at each phase end leaves only the
// last 2 stage units in flight => tile t+1 complete by end of (t,h1);
// first read of tile t+1 frags is at (t,h1) issue -> used at (t+1,h0).
// Tail stages clamp to tile 63 (dummy, race-free).

__global__ __launch_bounds__(512, 2) void gemm_i8_kernel(
    const int8_t* __restrict__ A,     // [M][K] i8
    const int8_t* __restrict__ B,     // [N][K] i8
    const float* __restrict__ xs,     // [M]
    const float* __restrict__ ws,     // [N]
    float* __restrict__ C)            // [M][N] fp32
{
    __shared__ __align__(16) int8_t As[4][256 * 64];   // 64 KiB
    __shared__ __align__(16) int8_t Bs[4][256 * 64];   // 64 KiB

    const int tid  = threadIdx.x;
    const int lane = tid & 63;
    const int wave = tid >> 6;         // 0..7
    const int wm   = wave >> 2;        // 0..1 -> 128 rows each
    const int wn   = wave & 3;         // 0..3 -> 64 cols each
    const int r32  = lane & 31;
    const int g    = lane >> 5;        // k-half selector within fragment

    // T1: XCD-aware bijective swizzle. grid = 16 x 43 = 688 = 8 * 86 exactly.
    const int orig = blockIdx.x + (blockIdx.y << 4);
    const int work = (orig & 7) * 86 + (orig >> 3);
    const int m0 = (work & 15) * 256;
    const int n0 = (work >> 4) * 256;

    // staging: thread t -> LDS row t>>2 (+128 for 2nd load), physical slot t&3.
    const int srow   = tid >> 2;                       // 0..127
    const int schunk = (tid & 3) ^ ((tid >> 3) & 3);   // pre-swizzled source chunk
    const int8_t* gA = A + (size_t)(m0 + srow) * K_DIM + schunk * 16;
    const int8_t* gB = B + (size_t)(n0 + srow) * K_DIM + schunk * 16;
    const size_t half2 = (size_t)128 * K_DIM;          // rows 128..255
    const int wb = wave * 1024;                        // wave-uniform LDS base

    // read side: logical chunk = ks*2 + g, physical = chunk ^ ((row>>1)&3)
    const int fsw = (r32 >> 1) & 3;
    const int ck0 = ((0 + g) ^ fsw) * 16;              // ks=0 chunk byte offset
    const int ck1 = ((2 + g) ^ fsw) * 16;              // ks=1 chunk byte offset
    const int a_row0 = (wm * 128 + r32) * 64;          // + ai*2048
    const int b_row0 = (wn * 64  + r32) * 64;          // + bj*2048

    i32x16 acc[4][2];
#pragma unroll
    for (int i = 0; i < 4; i++)
#pragma unroll
        for (int j = 0; j < 2; j++) acc[i][j] = (i32x16)(0);

    i32x4 afX[4], afY[4], bfX[2], bfY[2];

#define STAGE_A(t, buf) do {                                                  \
        direct_load16(gA + (size_t)(t) * 64,         (char*)As[buf] + wb);    \
        direct_load16(gA + (size_t)(t) * 64 + half2, (char*)As[buf] + wb + 8192); \
    } while (0)
#define STAGE_B(t, buf) do {                                                  \
        direct_load16(gB + (size_t)(t) * 64,         (char*)Bs[buf] + wb);    \
        direct_load16(gB + (size_t)(t) * 64 + half2, (char*)Bs[buf] + wb + 8192); \
    } while (0)

// load the 4 A fragments (ai=0..3) for k-step chunk CK from buffer buf
#define LDA4(dst, buf, CK) do {                                               \
        const int8_t* _p = As[buf];                                           \
        _Pragma("unroll")                                                     \
        for (int _i = 0; _i < 4; _i++)                                        \
            dst[_i] = *(const i32x4*)(_p + a_row0 + _i * 2048 + (CK));        \
    } while (0)
// load the 2 B fragments (bj=0..1) for k-step chunk CK from buffer buf
#define LDB2(dst, buf, CK) do {                                               \
        const int8_t* _p = Bs[buf];                                           \
        dst[0] = *(const i32x4*)(_p + b_row0 + (CK));                         \
        dst[1] = *(const i32x4*)(_p + b_row0 + 2048 + (CK));                  \
    } while (0)
// MFMA cluster (8 x 32x32x32), then counted-vmcnt + single barrier
#define MM(AF, BF) do {                                                       \
        __builtin_amdgcn_s_setprio(1);                                        \
        _Pragma("unroll")                                                     \
        for (int _i = 0; _i < 4; _i++)                                        \
            _Pragma("unroll")                                                 \
            for (int _j = 0; _j < 2; _j++)                                    \
                acc[_i][_j] = __builtin_amdgcn_mfma_i32_32x32x32_i8(          \
                    AF[_i], BF[_j], acc[_i][_j], 0, 0, 0);                    \
        __builtin_amdgcn_s_setprio(0);                                        \
        asm volatile("s_waitcnt vmcnt(4)" ::: "memory");                      \
        __builtin_amdgcn_s_barrier();                                         \
    } while (0)

    // prologue: stage tiles 0,1,2; vmcnt(4) forces tiles 0,1 complete
    STAGE_A(0, 0); STAGE_B(0, 0);
    STAGE_A(1, 1); STAGE_B(1, 1);
    STAGE_A(2, 2); STAGE_B(2, 2);
    asm volatile("s_waitcnt vmcnt(4)" ::: "memory");
    __builtin_amdgcn_s_barrier();

    // initial fragments for (tile0, ks0)
    LDA4(afX, 0, ck0);
    LDB2(bfX, 0, ck0);

    for (int u = 0; u < 32; ++u) {
        const int t0 = 2 * u, t1 = t0 + 1;
        const int b0 = t0 & 3, b1 = t1 & 3, b2 = (t0 + 2) & 3;
        const int sb0 = (t0 + 3) & 3, sb1 = (t0 + 4) & 3;
        const int s0 = (t0 + 3 > 63) ? 63 : t0 + 3;
        const int s1 = (t0 + 4 > 63) ? 63 : t0 + 4;

        // (t0,ks0): compute afX*bfX; prefetch ks1 frags of t0
        LDA4(afY, b0, ck1); LDB2(bfY, b0, ck1); STAGE_A(s0, sb0); MM(afX, bfX);
        // (t0,ks1): compute afY*bfY; prefetch ks0 frags of t1
        LDA4(afX, b1, ck0); LDB2(bfX, b1, ck0); STAGE_B(s0, sb0); MM(afY, bfY);
        // (t1,ks0): compute afX*bfX; prefetch ks1 frags of t1
        LDA4(afY, b1, ck1); LDB2(bfY, b1, ck1); STAGE_A(s1, sb1); MM(afX, bfX);
        // (t1,ks1): compute afY*bfY; prefetch ks0 frags of t0+2 (dead on last u)
        LDA4(afX, b2, ck0); LDB2(bfX, b2, ck0); STAGE_B(s1, sb1); MM(afY, bfY);
    }

#undef MM
#undef LDB2
#undef LDA4
#undef STAGE_B
#undef STAGE_A

    // epilogue: fp32 rescale by xs[m]*ws[n]
    // C/D 32x32: col = lane&31, row = (reg&3) + 8*(reg>>2) + 4*(lane>>5)
    const int g4 = g * 4;
#pragma unroll
    for (int ai = 0; ai < 4; ai++) {
        const int mb = m0 + wm * 128 + ai * 32 + g4;
#pragma unroll
        for (int rq = 0; rq < 4; rq++) {
            float rs[4];
#pragma unroll
            for (int rr = 0; rr < 4; rr++) rs[rr] = xs[mb + rq * 8 + rr];
#pragma unroll
            for (int bj = 0; bj < 2; bj++) {
                const int n = n0 + wn * 64 + bj * 32 + r32;
                const float s = ws[n];
#pragma unroll
                for (int rr = 0; rr < 4; rr++)
                    C[(size_t)(mb + rq * 8 + rr) * N_DIM + n] =
                        (float)acc[ai][bj][rq * 4 + rr] * s * rs[rr];
            }
        }
    }
}

// ---- launcher ------------------------------------------------------------

extern "C" void kernel_launch(void* const* d_in, const int* in_sizes, int n_in,
                              void* d_out, int out_size, void* d_ws, size_t ws_size,
                              hipStream_t stream) {
    const float* x       = (const float*)d_in[0];   // [4096][4096]
    const int*   w_int   = (const int*)d_in[1];     // [11008][4096]
    const float* w_scale = (const float*)d_in[2];   // [11008]
    float*       out     = (float*)d_out;           // [4096][11008]

    // ws layout: Wq i8 (45,088,768 B) | Xq i8 (16,777,216 B) | xs f32 (16,384 B)
    int8_t* wq = (int8_t*)d_ws;
    int8_t* xq = (int8_t*)((char*)d_ws + (size_t)N_DIM * K_DIM);
    float*  xs = (float*)((char*)d_ws + (size_t)N_DIM * K_DIM + (size_t)M_DIM * K_DIM);

    cvt_w_kernel<<<dim3(N_DIM * K_DIM / 4 / 256), dim3(256), 0, stream>>>(w_int, wq);
    quant_x_kernel<<<dim3(M_DIM), dim3(256), 0, stream>>>(x, xq, xs);
    gemm_i8_kernel<<<dim3(M_DIM / 256, N_DIM / 256), dim3(512), 0, stream>>>(xq, wq, xs, w_scale, out);
}

// Round 6
// 545.305 us; speedup vs baseline: 1.0306x; 1.0306x over previous
//
#include <hip/hip_runtime.h>
#include <stdint.h>

// QuantizedLinear: x[8,512,4096] fp32, W[11008,4096] int8-in-int32, scale[11008] fp32
#define M_DIM 4096
#define N_DIM 11008
#define K_DIM 4096

typedef int i32x4 __attribute__((ext_vector_type(4)));

// async global->LDS, 16 bytes/lane. LDS dest = wave-uniform base + lane*16.
static __device__ __forceinline__ void direct_load16(const void* gptr, void* ldsptr) {
    __builtin_amdgcn_global_load_lds(
        (const __attribute__((address_space(1))) void*)gptr,
        (__attribute__((address_space(3))) void*)ldsptr,
        16, 0, 0);
}

// ---- W: int32 in [-127,127] -> int8, 4 elems/thread, coalesced both sides
__global__ __launch_bounds__(256) void cvt_w_kernel(const int* __restrict__ w,
                                                    int8_t* __restrict__ o) {
    int t = blockIdx.x * 256 + threadIdx.x;
    const int4* w4 = (const int4*)w;
    int4 a = w4[t];
    ((unsigned*)o)[t] = (a.x & 255) | ((a.y & 255) << 8) | ((a.z & 255) << 16) | (a.w << 24);
}

// ---- x: fp32 -> int8 with per-row absmax scale --------------------------
__global__ __launch_bounds__(256) void quant_x_kernel(const float* __restrict__ x,
                                                      int8_t* __restrict__ xq,
                                                      float* __restrict__ xs) {
    __shared__ float wmax[4];
    const int row = blockIdx.x;
    const int t = threadIdx.x;
    const float4* xr = (const float4*)(x + (size_t)row * K_DIM);

    float4 v[4];
    float am = 0.0f;
#pragma unroll
    for (int p = 0; p < 4; p++) {
        v[p] = xr[p * 256 + t];
        am = fmaxf(am, fmaxf(fmaxf(fabsf(v[p].x), fabsf(v[p].y)),
                             fmaxf(fabsf(v[p].z), fabsf(v[p].w))));
    }
#pragma unroll
    for (int o = 32; o > 0; o >>= 1)
        am = fmaxf(am, __shfl_xor(am, o));
    if ((t & 63) == 0) wmax[t >> 6] = am;
    __syncthreads();
    am = fmaxf(fmaxf(wmax[0], wmax[1]), fmaxf(wmax[2], wmax[3]));

    const float inv = 127.0f / am;
    int* oq = (int*)(xq + (size_t)row * K_DIM);
#pragma unroll
    for (int p = 0; p < 4; p++) {
        int qa = (int)rintf(v[p].x * inv);
        int qb = (int)rintf(v[p].y * inv);
        int qc = (int)rintf(v[p].z * inv);
        int qd = (int)rintf(v[p].w * inv);
        oq[p * 256 + t] = (qa & 255) | ((qb & 255) << 8) | ((qc & 255) << 16) | (qd << 24);
    }
    if (t == 0) xs[row] = am * (1.0f / 127.0f);
}

// ---- GEMM: C = (Aq . Bq^T) * xs[m] * ws[n] ------------------------------
// 256x256 tile, 512 thr = 8 waves (2M x 4N), BK=64, 16x16x64 MFMA (the
// verified zero-conflict config from r4). r6 change: MERGED SYNC — one
// unbarriered region per K-tile {12 ds_read_b128 + 4 stage instr + 32 MFMA},
// then ONE vmcnt(8) + ONE s_barrier per tile (64 sync points/block vs 128).
// Compiler pipelines reads under MFMAs inside the region; waves can drift a
// full tile, giving setprio role diversity.
//
// Staging: 4 LDS buffers (tile t -> buf t&3), depth-3: tile t stages tile
// t+3. vmcnt(8) at tile end leaves t+3,t+2 (8 instr) in flight and forces
// t+1 complete — one barrier before its first read. Write-after-read: buf
// (t+3)&3 holds t-1's data, last read before t's entry barrier => stage
// during t is race-free. Tail stages clamp to tile 63 (dummy writes into
// buffers never read again). XOR chunk swizzle (phys = chunk ^ ((row>>1)&3))
// on pre-swizzled source + read side: measured 0 bank conflicts.

__global__ __launch_bounds__(512, 2) void gemm_i8_kernel(
    const int8_t* __restrict__ A,     // [M][K] i8
    const int8_t* __restrict__ B,     // [N][K] i8
    const float* __restrict__ xs,     // [M]
    const float* __restrict__ ws,     // [N]
    float* __restrict__ C)            // [M][N] fp32
{
    __shared__ __align__(16) int8_t As[4][256 * 64];   // 64 KiB
    __shared__ __align__(16) int8_t Bs[4][256 * 64];   // 64 KiB

    const int tid  = threadIdx.x;
    const int lane = tid & 63;
    const int wave = tid >> 6;         // 0..7
    const int wm   = wave >> 2;        // 0..1 -> 128 rows each
    const int wn   = wave & 3;         // 0..3 -> 64 cols each
    const int quad = lane >> 4;
    const int r16  = lane & 15;

    // T1: XCD-aware bijective swizzle. grid = 16 x 43 = 688 = 8 * 86 exactly.
    const int orig = blockIdx.x + (blockIdx.y << 4);
    const int work = (orig & 7) * 86 + (orig >> 3);
    const int m0 = (work & 15) * 256;
    const int n0 = (work >> 4) * 256;

    // staging: thread t -> LDS row t>>2 (+128 for 2nd load), physical slot t&3.
    const int srow   = tid >> 2;                       // 0..127
    const int schunk = (tid & 3) ^ ((tid >> 3) & 3);   // pre-swizzled source chunk
    const int8_t* gA = A + (size_t)(m0 + srow) * K_DIM + schunk * 16;
    const int8_t* gB = B + (size_t)(n0 + srow) * K_DIM + schunk * 16;
    const size_t half2 = (size_t)128 * K_DIM;          // rows 128..255
    const int wb = wave * 1024;                        // wave-uniform LDS base

    // read side: logical chunk = quad, physical = quad ^ ((row>>1)&3)
    const int fsw   = (r16 >> 1) & 3;
    const int a_off = (wm * 128 + r16) * 64 + ((quad ^ fsw) * 16);  // + i*1024
    const int b_off = (wn * 64  + r16) * 64 + ((quad ^ fsw) * 16);  // + j*1024

    i32x4 acc[8][4];
#pragma unroll
    for (int i = 0; i < 8; i++)
#pragma unroll
        for (int j = 0; j < 4; j++) acc[i][j] = (i32x4)(0);

#define STAGE_A(t, buf) do {                                                  \
        direct_load16(gA + (size_t)(t) * 64,         (char*)As[buf] + wb);    \
        direct_load16(gA + (size_t)(t) * 64 + half2, (char*)As[buf] + wb + 8192); \
    } while (0)
#define STAGE_B(t, buf) do {                                                  \
        direct_load16(gB + (size_t)(t) * 64,         (char*)Bs[buf] + wb);    \
        direct_load16(gB + (size_t)(t) * 64 + half2, (char*)Bs[buf] + wb + 8192); \
    } while (0)

    // prologue: stage tiles 0,1,2; vmcnt(8) forces tile 0 complete
    STAGE_A(0, 0); STAGE_B(0, 0);
    STAGE_A(1, 1); STAGE_B(1, 1);
    STAGE_A(2, 2); STAGE_B(2, 2);
    asm volatile("s_waitcnt vmcnt(8)" ::: "memory");
    __builtin_amdgcn_s_barrier();

    for (int t = 0; t < 64; ++t) {
        const int b  = t & 3;
        const int sb = (t + 3) & 3;
        const int s  = (t + 3 > 63) ? 63 : t + 3;

        // one merged region per tile: reads + stages + MFMA, no internal sync
        const int8_t* as = As[b];
        const int8_t* bs = Bs[b];
        i32x4 bf[4];
#pragma unroll
        for (int j = 0; j < 4; j++)
            bf[j] = *(const i32x4*)(bs + b_off + j * 1024);
        i32x4 af[8];
#pragma unroll
        for (int i = 0; i < 8; i++)
            af[i] = *(const i32x4*)(as + a_off + i * 1024);

        STAGE_A(s, sb);
        STAGE_B(s, sb);

        __builtin_amdgcn_s_setprio(1);
#pragma unroll
        for (int i = 0; i < 8; i++)
#pragma unroll
            for (int j = 0; j < 4; j++)
                acc[i][j] = __builtin_amdgcn_mfma_i32_16x16x64_i8(
                    af[i], bf[j], acc[i][j], 0, 0, 0);
        __builtin_amdgcn_s_setprio(0);

        asm volatile("s_waitcnt vmcnt(8)" ::: "memory");
        __builtin_amdgcn_s_barrier();
    }

#undef STAGE_B
#undef STAGE_A

    // epilogue: fp32 rescale by xs[m]*ws[n]; C/D frag: col=r16, row=quad*4+r
#pragma unroll
    for (int i = 0; i < 8; i++) {
        const int mrow = m0 + wm * 128 + i * 16 + quad * 4;
        float rsc[4];
#pragma unroll
        for (int r = 0; r < 4; r++) rsc[r] = xs[mrow + r];
#pragma unroll
        for (int j = 0; j < 4; j++) {
            const int n = n0 + wn * 64 + j * 16 + r16;
            const float sc = ws[n];
#pragma unroll
            for (int r = 0; r < 4; r++)
                C[(size_t)(mrow + r) * N_DIM + n] = (float)acc[i][j][r] * sc * rsc[r];
        }
    }
}

// ---- launcher ------------------------------------------------------------

extern "C" void kernel_launch(void* const* d_in, const int* in_sizes, int n_in,
                              void* d_out, int out_size, void* d_ws, size_t ws_size,
                              hipStream_t stream) {
    const float* x       = (const float*)d_in[0];   // [4096][4096]
    const int*   w_int   = (const int*)d_in[1];     // [11008][4096]
    const float* w_scale = (const float*)d_in[2];   // [11008]
    float*       out     = (float*)d_out;           // [4096][11008]

    // ws layout: Wq i8 (45,088,768 B) | Xq i8 (16,777,216 B) | xs f32 (16,384 B)
    int8_t* wq = (int8_t*)d_ws;
    int8_t* xq = (int8_t*)((char*)d_ws + (size_t)N_DIM * K_DIM);
    float*  xs = (float*)((char*)d_ws + (size_t)N_DIM * K_DIM + (size_t)M_DIM * K_DIM);

    cvt_w_kernel<<<dim3(N_DIM * K_DIM / 4 / 256), dim3(256), 0, stream>>>(w_int, wq);
    quant_x_kernel<<<dim3(M_DIM), dim3(256), 0, stream>>>(x, xq, xs);
    gemm_i8_kernel<<<dim3(M_DIM / 256, N_DIM / 256), dim3(512), 0, stream>>>(xq, wq, xs, w_scale, out);
}